// Round 7
// baseline (1390.724 us; speedup 1.0000x reference)
//
#include <hip/hip_runtime.h>
#include <hip/hip_cooperative_groups.h>
#include <math.h>

namespace cg = cooperative_groups;
typedef float4 f4;
typedef float2 f2;

#define NT 1024         // 16 waves/block, 4 waves/SIMD; pair (g, g+8) shares row-group g
#define RB 32           // rows per block; GRID=256 (cooperative cap)

// ---------------- workspace float offsets (weights + partials only) -------
#define WS_WR    0          // WR[128][256]: [k][0:128]=W2T row k, [k][128:256]=R row k
#define WS_PART  32768      // [10][256] err partials
#define WS_TOTAL 35328

// ---------------- LDS float offsets (~118.5 KB) ---------------------------
#define L_W1T   0           // [32][128]  W1T[j][h] = W1[h][j]
#define L_C3T   4096        // [32][132]  C3T[c][b] = C3[b][c]
#define L_PT    8320        // [32][36]   PT[c][q] = P[q][c]
#define L_XW    9472        // [8][32][4]  per-group x, k-major: XW[g][x][r]
#define L_H1W   10496       // [8][128][4] per-group h1: H1W[g][h][r]
#define L_H2W   14592       // [8][128][4] per-group h2
#define L_KZ    18688       // [7][32][36] k_z, pitch 36
#define L_KL    26752       // [7][32]     k_l
#define L_YZ    26976       // [32][36]    y_z
#define L_Y1Z   28128       // [32][36]    y1_z
#define L_YL    29280       // [32]
#define L_Y1L   29312       // [32]
#define L_B1    29344
#define L_B2    29472
#define L_C0    29600
#define L_GS    29632       // [8][32]
#define L_AAUG  29888       // [8][16]
#define L_AINVG 30016       // [8][32]
#define L_MISC  30272       // [0]=trP
#define L_DL    30276       // [8 group][2 hi][4 row] dl partials
#define LDS_FLOATS 30340
#define L_RED   L_H1W       // [16] alias — H1W dead during error reduction
#define L_P     L_H2W       // [32][32] init-only alias
#define L_IP    (L_H2W + 1024) // [32][32] init-only alias
#define L_IPW3  L_KZ        // [32][128] init-only alias

__device__ const float ACO[5][5] = {
  { 0.2f, 0.f, 0.f, 0.f, 0.f },
  { (float)(3.0/40.0), (float)(9.0/40.0), 0.f, 0.f, 0.f },
  { (float)(44.0/45.0), (float)(-56.0/15.0), (float)(32.0/9.0), 0.f, 0.f },
  { (float)(19372.0/6561.0), (float)(-25360.0/2187.0), (float)(64448.0/6561.0), (float)(-212.0/729.0), 0.f },
  { (float)(9017.0/3168.0), (float)(-355.0/33.0), (float)(46732.0/5247.0), (float)(49.0/176.0), (float)(-5103.0/18656.0) }
};

#define B1C ((float)(35.0/384.0))
#define B3C ((float)(500.0/1113.0))
#define B4C ((float)(125.0/192.0))
#define B5C ((float)(-2187.0/6784.0))
#define B6C ((float)(11.0/84.0))

#define E1C ((float)(35.0/384.0 - 5179.0/57600.0))
#define E3C ((float)(500.0/1113.0 - 7571.0/16695.0))
#define E4C ((float)(125.0/192.0 - 393.0/640.0))
#define E5C ((float)(-2187.0/6784.0 + 92097.0/339200.0))
#define E6C ((float)(11.0/84.0 - 187.0/2100.0))
#define E7C ((float)(-1.0/40.0))

__device__ __forceinline__ f4 ld4(const float* p){ return *(const f4*)p; }
__device__ __forceinline__ void st4(float* p, f4 v){ *(f4*)p = v; }

// assemble: wave (g,hi) computes its own 2 rows (4g+2hi+rr), 1 col/lane.
// Wave-local w.r.t. KZ (phase 3 of same wave wrote these rows) and XW slots.
__device__ __forceinline__ void assemble_x(float* lds, int tid, float dtc,
                                           const float* co, int np)
{
  const int w = tid >> 6, lane = tid & 63;
  const int g = w & 7, hi = w >> 3;
  const int rr = lane >> 5, c = lane & 31;
  const int o = (4 * g + 2 * hi + rr) * 36 + c;
  float y = lds[L_YZ + o];
  float s = 0.f;
  for (int p = 0; p < np; p++) s += co[p] * lds[L_KZ + p * 1152 + o];
  lds[L_XW + g * 128 + c * 4 + 2 * hi + rr] = y + dtc * s;
}

// f-eval at 16 waves: pair (g, g+8) shares row-group g.
// phase 1: own 2 rows, all 128 h (wave-local)        -> barrier 1
// phase 2: col-half (64*hi), all k, 4 rows of group  -> barrier 2 (+tiny dl xchg)
// phase 3: own 2 rows, all 128 b
__device__ void eval_f(float* lds, const float* __restrict__ ws, int tid,
                       float trP, int kout)
{
  const int w = tid >> 6, lane = tid & 63;
  const int g = w & 7, hi = w >> 3;
  float* XWp = &lds[L_XW + g * 128];
  float* H1p = &lds[L_H1W + g * 512];
  float* H2p = &lds[L_H2W + g * 512];

  // ---- phase 1: h1 = relu(x @ W1^T + b1), own 2 rows ----
  {
    const int cg = lane & 31, kh = lane >> 5;
    float a1[4][2];
#pragma unroll
    for (int i = 0; i < 4; i++){ a1[i][0] = 0.f; a1[i][1] = 0.f; }
#pragma unroll 4
    for (int t = 0; t < 16; t++){
      const int k = kh * 16 + t;
      f2 xv = *(const f2*)&XWp[k * 4 + 2 * hi];       // broadcast
      f4 wv = ld4(&lds[L_W1T + k * 128 + 4 * cg]);
      const float* wp = (const float*)&wv;
#pragma unroll
      for (int i = 0; i < 4; i++){
        a1[i][0] += wp[i] * xv.x;
        a1[i][1] += wp[i] * xv.y;
      }
    }
#pragma unroll
    for (int i = 0; i < 4; i++){
      a1[i][0] += __shfl_xor(a1[i][0], 32);
      a1[i][1] += __shfl_xor(a1[i][1], 32);
    }
    if (kh == 0){
      f4 b1v = ld4(&lds[L_B1 + 4 * cg]);
      const float* b1p = (const float*)&b1v;
#pragma unroll
      for (int i = 0; i < 4; i++){
        f2 hv;
        hv.x = fmaxf(a1[i][0] + b1p[i], 0.f);
        hv.y = fmaxf(a1[i][1] + b1p[i], 0.f);
        *(f2*)&H1p[(4 * cg + i) * 4 + 2 * hi] = hv;
      }
    }
  }
  __syncthreads();               // barrier 1: H1[g] complete (4 rows x 128 h)

  // ---- phase 2: cols 64*hi+4*ccg..+3, all k (k = 4t+kq: conflict-free H1) ----
  const int ccg = lane & 15, kq = lane >> 4;
  float ah[4][4], at[4][4];
#pragma unroll
  for (int i = 0; i < 4; i++)
#pragma unroll
    for (int j = 0; j < 4; j++){ ah[i][j] = 0.f; at[i][j] = 0.f; }
  const f4* WR4 = (const f4*)&ws[WS_WR];   // row k = 64 f4: [0:32)=W2T, [32:64)=R
#pragma unroll 4
  for (int t = 0; t < 32; t++){
    const int k = 4 * t + kq;
    f4 wv = WR4[k * 64 + 16 * hi + ccg];
    f4 rv = WR4[k * 64 + 32 + 16 * hi + ccg];
    f4 av = ld4(&H1p[k * 4]);                 // broadcast across ccg
    const float* wp = (const float*)&wv;
    const float* rp = (const float*)&rv;
    const float* ap = (const float*)&av;
    float m[4];
#pragma unroll
    for (int j = 0; j < 4; j++) m[j] = (ap[j] > 0.f) ? 1.f : 0.f;
#pragma unroll
    for (int i = 0; i < 4; i++)
#pragma unroll
      for (int j = 0; j < 4; j++){
        ah[i][j] += wp[i] * ap[j];
        at[i][j] += rp[i] * m[j];
      }
  }
  // reduce over kq (4 partials)
#pragma unroll
  for (int i = 0; i < 4; i++)
#pragma unroll
    for (int j = 0; j < 4; j++){
      ah[i][j] += __shfl_xor(ah[i][j], 16);
      ah[i][j] += __shfl_xor(ah[i][j], 32);
      at[i][j] += __shfl_xor(at[i][j], 16);
      at[i][j] += __shfl_xor(at[i][j], 32);
    }
  float dl[4] = {0.f, 0.f, 0.f, 0.f};
  if (kq == 0){
    f4 b2v = ld4(&lds[L_B2 + 64 * hi + 4 * ccg]);
    const float* b2p = (const float*)&b2v;
#pragma unroll
    for (int i = 0; i < 4; i++){
      f4 hv; float* hp = (float*)&hv;
#pragma unroll
      for (int j = 0; j < 4; j++){
        float pre = ah[i][j] + b2p[i];
        hp[j] = fmaxf(pre, 0.f);
        if (pre > 0.f) dl[j] += at[i][j];
      }
      st4(&H2p[(64 * hi + 4 * ccg + i) * 4], hv);
    }
  }
#pragma unroll
  for (int mk = 1; mk < 16; mk <<= 1){
#pragma unroll
    for (int j = 0; j < 4; j++) dl[j] += __shfl_xor(dl[j], mk);
  }
  if (lane == 0){
#pragma unroll
    for (int j = 0; j < 4; j++) lds[L_DL + g * 8 + hi * 4 + j] = dl[j];
  }
  __syncthreads();               // barrier 2: H2[g] (both col-halves) + DL

  if (hi == 0 && lane < 4)
    lds[L_KL + kout * 32 + 4 * g + lane] =
        lds[L_DL + g * 8 + lane] + lds[L_DL + g * 8 + 4 + lane] + trP;

  // ---- phase 3: dz own 2 rows, 1 col/lane, b split over lane halves ----
  {
    const int c3 = lane & 31, bh = lane >> 5;
    float a30 = 0.f, a31 = 0.f;
    const int bb = bh * 64;
#pragma unroll 4
    for (int t = 0; t < 16; t++){
      f4 cv = ld4(&lds[L_C3T + c3 * 132 + bb + 4 * t]);
      const float* cp = (const float*)&cv;
#pragma unroll
      for (int u = 0; u < 4; u++){
        f2 av = *(const f2*)&H2p[(bb + 4 * t + u) * 4 + 2 * hi];
        a30 += av.x * cp[u];
        a31 += av.y * cp[u];
      }
    }
    const int qq = bh * 16;
#pragma unroll
    for (int t = 0; t < 4; t++){
      f4 pv = ld4(&lds[L_PT + c3 * 36 + qq + 4 * t]);
      const float* pp = (const float*)&pv;
#pragma unroll
      for (int u = 0; u < 4; u++){
        f2 xv = *(const f2*)&XWp[(qq + 4 * t + u) * 4 + 2 * hi];
        a30 += xv.x * pp[u];
        a31 += xv.y * pp[u];
      }
    }
    a30 += __shfl_xor(a30, 32);
    a31 += __shfl_xor(a31, 32);
    if (bh == 0){
      float c0v = lds[L_C0 + c3];
      lds[L_KZ + kout * 1152 + (4 * g + 2 * hi + 0) * 36 + c3] = -(a30 + c0v);
      lds[L_KZ + kout * 1152 + (4 * g + 2 * hi + 1) * 36 + c3] = -(a31 + c0v);
    }
  }
}

__global__ void __launch_bounds__(NT, 4)
qpnf_kernel(const float* __restrict__ z, const float* __restrict__ Gw,
            const float* __restrict__ W1g, const float* __restrict__ b1g,
            const float* __restrict__ W2g, const float* __restrict__ b2g,
            const float* __restrict__ W3g, const float* __restrict__ b3g,
            const float* __restrict__ Tg, float* __restrict__ out,
            float* __restrict__ ws)
{
  __shared__ float lds[LDS_FLOATS];
  const int tid = threadIdx.x;
  const int bid = blockIdx.x;
  const int r0 = bid * RB;
  cg::grid_group grid = cg::this_grid();

  // ================= init =================
  for (int idx = tid; idx < 4096; idx += NT){   // W1T[j][h] = W1[h][j]
    int h = idx >> 5, j = idx & 31;
    lds[L_W1T + j * 128 + h] = W1g[idx];
  }
  if (tid < 128){ lds[L_B1 + tid] = b1g[tid]; lds[L_B2 + tid] = b2g[tid]; }
  if (tid < 256) lds[L_GS + tid] = Gw[tid];
  __syncthreads();

  if (tid < 64){                              // A = G G^T (8x8), augmented
    int i = tid >> 3, j = tid & 7;
    float s = 0.f;
    for (int k = 0; k < 32; k++) s += lds[L_GS + i * 32 + k] * lds[L_GS + j * 32 + k];
    lds[L_AAUG + i * 16 + j] = s;
    lds[L_AAUG + i * 16 + 8 + j] = (i == j) ? 1.f : 0.f;
  }
  __syncthreads();
  if (tid == 0){                              // Gauss-Jordan, partial pivoting
    float* A = &lds[L_AAUG];
    for (int c = 0; c < 8; c++){
      int p = c; float mx = fabsf(A[c * 16 + c]);
      for (int r = c + 1; r < 8; r++){
        float v = fabsf(A[r * 16 + c]);
        if (v > mx){ mx = v; p = r; }
      }
      if (p != c)
        for (int q = 0; q < 16; q++){ float t = A[c*16+q]; A[c*16+q] = A[p*16+q]; A[p*16+q] = t; }
      float pv = 1.0f / A[c * 16 + c];
      for (int q = 0; q < 16; q++) A[c * 16 + q] *= pv;
      for (int r = 0; r < 8; r++) if (r != c){
        float fct = A[r * 16 + c];
        for (int q = 0; q < 16; q++) A[r * 16 + q] -= fct * A[c * 16 + q];
      }
    }
  }
  __syncthreads();
  if (tid < 256){                              // AinvG[m][d]
    int m = tid >> 5, d = tid & 31;
    float s = 0.f;
    for (int q = 0; q < 8; q++) s += lds[L_AAUG + m * 16 + 8 + q] * lds[L_GS + q * 32 + d];
    lds[L_AINVG + m * 32 + d] = s;
  }
  __syncthreads();
  {                                            // P = G^T AinvG (alias in H2W)
    int i = tid >> 5, j = tid & 31;
    float s = 0.f;
    for (int m = 0; m < 8; m++) s += lds[L_GS + m * 32 + i] * lds[L_AINVG + m * 32 + j];
    lds[L_P + i * 32 + j] = s;
  }
  __syncthreads();
  float* IPl = &lds[L_IP];                     // IP aliases H2W+1024 during init
  {
    int i = tid >> 5, j = tid & 31;
    IPl[i * 32 + j] = ((i == j) ? 1.f : 0.f) - lds[L_P + i * 32 + j];
  }
  if (tid == 0){
    float s = 0.f;
    for (int i = 0; i < 32; i++) s += lds[L_P + i * 32 + i];
    lds[L_MISC] = s;                           // trP
  }
  __syncthreads();
  for (int idx = tid; idx < 4096; idx += NT){  // C3T[c][b] = sum_i W3[i][b] IP[i][c]
    int b = idx & 127, c = idx >> 7;
    float s = 0.f;
    for (int i = 0; i < 32; i++) s += W3g[i * 128 + b] * IPl[i * 32 + c];
    lds[L_C3T + c * 132 + b] = s;
  }
  {                                            // PT[c][q] = P[q][c]
    int c = tid >> 5, q = tid & 31;
    lds[L_PT + c * 36 + q] = lds[L_P + q * 32 + c];
  }
  if (tid < 32){                               // c0 = b3 @ IP
    float s = 0.f;
    for (int i = 0; i < 32; i++) s += b3g[i] * IPl[i * 32 + tid];
    lds[L_C0 + tid] = s;
  }
  for (int idx = tid; idx < 4096; idx += NT){  // IPW3[j][b] (aliases KZ)
    int j = idx >> 7, b = idx & 127;
    float s = 0.f;
    for (int k = 0; k < 32; k++) s += IPl[j * 32 + k] * W3g[k * 128 + b];
    lds[L_IPW3 + j * 128 + b] = s;
  }
  __syncthreads();
  if (bid < 128 && tid < 128){                 // R row a=bid -> WR[a][128+b]
    int a = bid;
    float s = 0.f;
    for (int j = 0; j < 32; j++) s += W1g[a * 32 + j] * lds[L_IPW3 + j * 128 + tid];
    ws[WS_WR + a * 256 + 128 + tid] = s * W2g[tid * 128 + a];
  }
  if (bid >= 128 && tid < 128){                // W2T row a -> WR[a][b]
    int a = bid - 128;
    ws[WS_WR + a * 256 + tid] = W2g[tid * 128 + a];
  }
  if (tid < 256){                              // y0 = [z, 0] -> LDS
    const int r = tid >> 3, jj = (tid & 7) * 4;
    st4(&lds[L_YZ + r * 36 + jj], ld4(&z[(r0 + r) * 32 + jj]));
  }
  if (tid < RB) lds[L_YL + tid] = 0.f;

  const float trP = lds[L_MISC];
  const float t1 = 2.0f * Tg[0];

  grid.sync();

  // ================= main adaptive RK loop =================
  float t_cur = 0.f, dt_cur = 0.25f;
  bool prev_acc = false;

  for (int step = 0; step < 10; step++){
    if (t_cur >= t1 - 1e-9f) break;            // uniform across grid
    const float dtc = fminf(dt_cur, t1 - t_cur);

    // stages 1..6
    for (int s = 1; s <= 6; s++){
      if (s == 1 && step > 0){
        if (prev_acc){                         // FSAL: k1 = previous k7
          if (tid < 256){
            const int r = tid >> 3, jj = (tid & 7) * 4;
            const int o = r * 36 + jj;
            st4(&lds[L_KZ + o], ld4(&lds[L_KZ + 6 * 1152 + o]));
          }
          if (tid < RB) lds[L_KL + tid] = lds[L_KL + 6 * 32 + tid];
        }                                       // rejected: k1 = f(y) unchanged
        __syncthreads();   // KZ0/KL0 + accepted-YZ visible to all waves
        continue;
      }
      assemble_x(lds, tid, dtc, ACO[s >= 2 ? s - 2 : 0], s - 1);
      eval_f(lds, ws, tid, trP, s - 1);
    }

    // stage 7: y1, k7 = f(y1), error estimate
    __syncthreads();                           // all waves' KZ/KL visible
    if (tid < 256){
      const int r = tid >> 3, jj = (tid & 7) * 4;
      const int o = r * 36 + jj;
      f4 y   = ld4(&lds[L_YZ + o]);
      f4 k1v = ld4(&lds[L_KZ + 0 * 1152 + o]);
      f4 k3v = ld4(&lds[L_KZ + 2 * 1152 + o]);
      f4 k4v = ld4(&lds[L_KZ + 3 * 1152 + o]);
      f4 k5v = ld4(&lds[L_KZ + 4 * 1152 + o]);
      f4 k6v = ld4(&lds[L_KZ + 5 * 1152 + o]);
      f4 x;
      x.x = y.x + dtc * (B1C*k1v.x + B3C*k3v.x + B4C*k4v.x + B5C*k5v.x + B6C*k6v.x);
      x.y = y.y + dtc * (B1C*k1v.y + B3C*k3v.y + B4C*k4v.y + B5C*k5v.y + B6C*k6v.y);
      x.z = y.z + dtc * (B1C*k1v.z + B3C*k3v.z + B4C*k4v.z + B5C*k5v.z + B6C*k6v.z);
      x.w = y.w + dtc * (B1C*k1v.w + B3C*k3v.w + B4C*k4v.w + B5C*k5v.w + B6C*k6v.w);
      st4(&lds[L_Y1Z + o], x);
      float* XWp = &lds[L_XW + (r >> 2) * 128];   // scatter into group's XW
      const int rr = r & 3;
      XWp[(jj + 0) * 4 + rr] = x.x;
      XWp[(jj + 1) * 4 + rr] = x.y;
      XWp[(jj + 2) * 4 + rr] = x.z;
      XWp[(jj + 3) * 4 + rr] = x.w;
    }
    if (tid < RB){
      float s = B1C * lds[L_KL + 0*32 + tid] + B3C * lds[L_KL + 2*32 + tid]
              + B4C * lds[L_KL + 3*32 + tid] + B5C * lds[L_KL + 4*32 + tid]
              + B6C * lds[L_KL + 5*32 + tid];
      lds[L_Y1L + tid] = lds[L_YL + tid] + dtc * s;
    }
    __syncthreads();                           // XW scatter was cross-wave
    eval_f(lds, ws, tid, trP, 6);
    __syncthreads();                           // all waves' k7 visible

    float sacc = 0.f;
    if (tid < 256){
      const int r = tid >> 3, jj = (tid & 7) * 4;
      const int o = r * 36 + jj;
      f4 k1v = ld4(&lds[L_KZ + 0 * 1152 + o]);
      f4 k3v = ld4(&lds[L_KZ + 2 * 1152 + o]);
      f4 k4v = ld4(&lds[L_KZ + 3 * 1152 + o]);
      f4 k5v = ld4(&lds[L_KZ + 4 * 1152 + o]);
      f4 k6v = ld4(&lds[L_KZ + 5 * 1152 + o]);
      f4 k7v = ld4(&lds[L_KZ + 6 * 1152 + o]);
      f4 yv  = ld4(&lds[L_YZ + o]);
      f4 y1v = ld4(&lds[L_Y1Z + o]);
      float ev, tol, q;
      ev = dtc * (E1C*k1v.x + E3C*k3v.x + E4C*k4v.x + E5C*k5v.x + E6C*k6v.x + E7C*k7v.x);
      tol = 1e-5f + 1e-5f * fmaxf(fabsf(yv.x), fabsf(y1v.x)); q = ev / tol; sacc += q * q;
      ev = dtc * (E1C*k1v.y + E3C*k3v.y + E4C*k4v.y + E5C*k5v.y + E6C*k6v.y + E7C*k7v.y);
      tol = 1e-5f + 1e-5f * fmaxf(fabsf(yv.y), fabsf(y1v.y)); q = ev / tol; sacc += q * q;
      ev = dtc * (E1C*k1v.z + E3C*k3v.z + E4C*k4v.z + E5C*k5v.z + E6C*k6v.z + E7C*k7v.z);
      tol = 1e-5f + 1e-5f * fmaxf(fabsf(yv.z), fabsf(y1v.z)); q = ev / tol; sacc += q * q;
      ev = dtc * (E1C*k1v.w + E3C*k3v.w + E4C*k4v.w + E5C*k5v.w + E6C*k6v.w + E7C*k7v.w);
      tol = 1e-5f + 1e-5f * fmaxf(fabsf(yv.w), fabsf(y1v.w)); q = ev / tol; sacc += q * q;
    }
    if (tid < RB){
      float evl = dtc * (E1C * lds[L_KL + 0*32 + tid] + E3C * lds[L_KL + 2*32 + tid]
                + E4C * lds[L_KL + 3*32 + tid] + E5C * lds[L_KL + 4*32 + tid]
                + E6C * lds[L_KL + 5*32 + tid] + E7C * lds[L_KL + 6*32 + tid]);
      float toll = 1e-5f + 1e-5f * fmaxf(fabsf(lds[L_YL + tid]), fabsf(lds[L_Y1L + tid]));
      float ql = evl / toll; sacc += ql * ql;
    }
    // block reduction: wave butterflies + 16-wide LDS combine
#pragma unroll
    for (int mk = 1; mk < 64; mk <<= 1) sacc += __shfl_xor(sacc, mk, 64);
    if ((tid & 63) == 0) lds[L_RED + (tid >> 6)] = sacc;   // RED aliases dead H1W
    __syncthreads();
    if (tid == 0){
      float s = 0.f;
      for (int i = 0; i < 16; i++) s += lds[L_RED + i];
      ws[WS_PART + step * 256 + bid] = s;
    }

    grid.sync();

    // deterministic global reduction (every block, identical order)
    float ps = 0.f;
    if (tid < 256) ps = ws[WS_PART + step * 256 + tid];
#pragma unroll
    for (int mk = 1; mk < 64; mk <<= 1) ps += __shfl_xor(ps, mk, 64);
    if (tid < 256 && (tid & 63) == 0) lds[L_RED + (tid >> 6)] = ps;
    __syncthreads();
    const float errn = sqrtf((lds[L_RED+0] + lds[L_RED+1] + lds[L_RED+2] + lds[L_RED+3])
                             / 270336.0f);
    __syncthreads();             // protect RED(=H1W) before next phase-1 overwrite

    const bool accept = (errn <= 1.0f);
    if (accept){                               // y <- y1 (visible via s==1 barrier)
      if (tid < 256){
        const int r = tid >> 3, jj = (tid & 7) * 4;
        const int o = r * 36 + jj;
        st4(&lds[L_YZ + o], ld4(&lds[L_Y1Z + o]));
      }
      if (tid < RB) lds[L_YL + tid] = lds[L_Y1L + tid];
      t_cur += dtc;
    }
    float fac = 0.9f * powf(errn, -0.2f);
    fac = fminf(fmaxf(fac, 0.2f), 10.0f);
    dt_cur = fminf(fmaxf(dtc * fac, 1e-6f), t1);
    prev_acc = accept;
  }

  // ---- output: yT[:, :d] ----
  __syncthreads();
  if (tid < 256){
    const int r = tid >> 3, jj = (tid & 7) * 4;
    st4(&out[(r0 + r) * 32 + jj], ld4(&lds[L_YZ + r * 36 + jj]));
  }
}

extern "C" void kernel_launch(void* const* d_in, const int* in_sizes, int n_in,
                              void* d_out, int out_size, void* d_ws, size_t ws_size,
                              hipStream_t stream)
{
  (void)in_sizes; (void)n_in; (void)out_size;
  const float* z  = (const float*)d_in[0];
  const float* Gw = (const float*)d_in[1];
  const float* W1 = (const float*)d_in[2];
  const float* b1 = (const float*)d_in[3];
  const float* W2 = (const float*)d_in[4];
  const float* b2 = (const float*)d_in[5];
  const float* W3 = (const float*)d_in[6];
  const float* b3 = (const float*)d_in[7];
  const float* T  = (const float*)d_in[8];
  float* out = (float*)d_out;
  float* ws  = (float*)d_ws;
  if (ws_size < (size_t)WS_TOTAL * sizeof(float)) return;

  void* args[] = { (void*)&z, (void*)&Gw, (void*)&W1, (void*)&b1, (void*)&W2,
                   (void*)&b2, (void*)&W3, (void*)&b3, (void*)&T, (void*)&out,
                   (void*)&ws };
  hipLaunchCooperativeKernel((const void*)qpnf_kernel, dim3(256), dim3(NT),
                             args, 0, stream);
}

// Round 8
// 1236.366 us; speedup vs baseline: 1.1248x; 1.1248x over previous
//
#include <hip/hip_runtime.h>
#include <hip/hip_cooperative_groups.h>
#include <math.h>

namespace cg = cooperative_groups;
typedef float4 f4;
typedef float2 f2;
typedef float v2f __attribute__((ext_vector_type(2)));

#define NT 512          // 8 waves/block; wave-local dataflow: wave w owns rows 4w..4w+3
#define RB 32           // rows per block; GRID=256 (cooperative cap)

// ---------------- workspace float offsets (weights + partials only) -------
#define WS_WR    0          // WR[128][256]: [k][0:128]=W2T row k, [k][128:256]=R row k
#define WS_PART  32768      // [10][256] err partials
#define WS_TOTAL 35328

// ---------------- LDS float offsets (118.3 KB) ----------------------------
#define L_W1T   0           // [32][128]  W1T[j][h] = W1[h][j]
#define L_C3T   4096        // [32][132]  C3T[c][b] = C3[b][c]
#define L_PT    8320        // [32][36]   PT[c][q] = P[q][c]
#define L_XW    9472        // [8][32][4]  per-wave x, k-major: XW[w][k][r]
#define L_H1W   10496       // [8][128][4] per-wave h1, h-major: H1W[w][h][r]
#define L_H2W   14592       // [8][128][4] per-wave h2
#define L_KZ    18688       // [7][32][36] k_z, pitch 36
#define L_KL    26752       // [7][32]     k_l
#define L_YZ    26976       // [32][36]    y_z
#define L_Y1Z   28128       // [32][36]    y1_z
#define L_YL    29280       // [32]
#define L_Y1L   29312       // [32]
#define L_B1    29344
#define L_B2    29472
#define L_C0    29600
#define L_GS    29632       // [8][32]
#define L_AAUG  29888       // [8][16]
#define L_AINVG 30016       // [8][32]
#define L_MISC  30272       // [0]=trP
#define LDS_FLOATS 30276
#define L_RED   L_H1W       // [8] alias — H1W dead during error reduction
#define L_P     L_H2W       // [32][32] init-only alias
#define L_IP    (L_H2W + 1024) // [32][32] init-only alias
#define L_IPW3  L_KZ        // [32][128] init-only alias

__device__ const float ACO[5][5] = {
  { 0.2f, 0.f, 0.f, 0.f, 0.f },
  { (float)(3.0/40.0), (float)(9.0/40.0), 0.f, 0.f, 0.f },
  { (float)(44.0/45.0), (float)(-56.0/15.0), (float)(32.0/9.0), 0.f, 0.f },
  { (float)(19372.0/6561.0), (float)(-25360.0/2187.0), (float)(64448.0/6561.0), (float)(-212.0/729.0), 0.f },
  { (float)(9017.0/3168.0), (float)(-355.0/33.0), (float)(46732.0/5247.0), (float)(49.0/176.0), (float)(-5103.0/18656.0) }
};

#define B1C ((float)(35.0/384.0))
#define B3C ((float)(500.0/1113.0))
#define B4C ((float)(125.0/192.0))
#define B5C ((float)(-2187.0/6784.0))
#define B6C ((float)(11.0/84.0))

#define E1C ((float)(35.0/384.0 - 5179.0/57600.0))
#define E3C ((float)(500.0/1113.0 - 7571.0/16695.0))
#define E4C ((float)(125.0/192.0 - 393.0/640.0))
#define E5C ((float)(-2187.0/6784.0 + 92097.0/339200.0))
#define E6C ((float)(11.0/84.0 - 187.0/2100.0))
#define E7C ((float)(-1.0/40.0))

__device__ __forceinline__ f4 ld4(const float* p){ return *(const f4*)p; }
__device__ __forceinline__ void st4(float* p, f4 v){ *(f4*)p = v; }

// packed fp32 FMA, broadcasting src0.lo / src0.hi to both halves via op_sel.
// d.lo += s.lo*b.lo ; d.hi += s.lo*b.hi     (pk_lo)
// d.lo += s.hi*b.lo ; d.hi += s.hi*b.hi     (pk_hi)
__device__ __forceinline__ void pk_lo(v2f& d, v2f s, v2f b){
  asm("v_pk_fma_f32 %0, %1, %2, %0 op_sel:[0,0,0] op_sel_hi:[0,1,1]"
      : "+v"(d) : "v"(s), "v"(b));
}
__device__ __forceinline__ void pk_hi(v2f& d, v2f s, v2f b){
  asm("v_pk_fma_f32 %0, %1, %2, %0 op_sel:[1,0,0] op_sel_hi:[1,1,1]"
      : "+v"(d) : "v"(s), "v"(b));
}
__device__ __forceinline__ v2f vlo(f4 v){ v2f r; r.x = v.x; r.y = v.y; return r; }
__device__ __forceinline__ v2f vhi(f4 v){ v2f r; r.x = v.z; r.y = v.w; return r; }

// wave-local assemble: x = y + dtc*sum_p co[p]*k[p] -> XW[w] (k-major).
__device__ __forceinline__ void assemble_x(float* lds, int tid, float dtc,
                                           const float* co, int np)
{
  const int w = tid >> 6, lane = tid & 63;
  const int r = lane >> 4;            // 0..3 local row
  const int c = (lane << 1) & 31;     // even col
  const int o = (4 * w + r) * 36 + c;
  f2 y = *(const f2*)&lds[L_YZ + o];
  float sx = 0.f, sy = 0.f;
  for (int p = 0; p < np; p++){
    f2 kv = *(const f2*)&lds[L_KZ + p * 1152 + o];
    sx += co[p] * kv.x; sy += co[p] * kv.y;
  }
  float* XWp = &lds[L_XW + w * 128];
  XWp[(c + 0) * 4 + r] = y.x + dtc * sx;
  XWp[(c + 1) * 4 + r] = y.y + dtc * sy;
}

// full f-eval, wave-local, barrier-free (R3 structure), v_pk_fma_f32 cores,
// ReLU mask recomputed inline from h1 (h1>0 <=> pre>0, exact) — no extra LDS.
__device__ void eval_f(float* lds, const float* __restrict__ ws, int tid,
                       float trP, int kout)
{
  const int w = tid >> 6, lane = tid & 63;
  const int cg = lane & 31, kh = lane >> 5;
  float* XWp = &lds[L_XW  + w * 128];
  float* H1p = &lds[L_H1W + w * 512];
  float* H2p = &lds[L_H2W + w * 512];

  // ---- issue first WR prefetch NOW: L2 latency hides under phase 1 ----
  const f4* WR4 = (const f4*)&ws[WS_WR];   // row k = 64 f4: [0:32)=W2T, [32:64)=R
  const int kb = kh * 64;
  f4 wb[4], rb[4];
#pragma unroll
  for (int u = 0; u < 4; u++){
    wb[u] = WR4[(kb + u) * 64 + cg];
    rb[u] = WR4[(kb + u) * 64 + 32 + cg];
  }

  // ---- phase 1: h1 = relu(x @ W1^T + b1) -> H1W[w] ----
  v2f a12[4][2];
#pragma unroll
  for (int i = 0; i < 4; i++)
#pragma unroll
    for (int jp = 0; jp < 2; jp++){ a12[i][jp].x = 0.f; a12[i][jp].y = 0.f; }
#pragma unroll 4
  for (int t = 0; t < 16; t++){
    const int k = kh * 16 + t;
    f4 xv = ld4(&XWp[k * 4]);                       // broadcast (4 rows)
    f4 wv = ld4(&lds[L_W1T + k * 128 + 4 * cg]);
    v2f x0 = vlo(xv), x1 = vhi(xv);
    v2f wA = vlo(wv), wB = vhi(wv);
    pk_lo(a12[0][0], wA, x0); pk_lo(a12[0][1], wA, x1);
    pk_hi(a12[1][0], wA, x0); pk_hi(a12[1][1], wA, x1);
    pk_lo(a12[2][0], wB, x0); pk_lo(a12[2][1], wB, x1);
    pk_hi(a12[3][0], wB, x0); pk_hi(a12[3][1], wB, x1);
  }
  float a1s[4][4];
#pragma unroll
  for (int i = 0; i < 4; i++){
    a1s[i][0] = a12[i][0].x; a1s[i][1] = a12[i][0].y;
    a1s[i][2] = a12[i][1].x; a1s[i][3] = a12[i][1].y;
  }
#pragma unroll
  for (int i = 0; i < 4; i++)
#pragma unroll
    for (int j = 0; j < 4; j++) a1s[i][j] += __shfl_xor(a1s[i][j], 32);
  if (kh == 0){
    f4 b1v = ld4(&lds[L_B1 + 4 * cg]);
    const float* b1p = (const float*)&b1v;
#pragma unroll
    for (int i = 0; i < 4; i++){
      f4 hv; float* hp = (float*)&hv;
#pragma unroll
      for (int j = 0; j < 4; j++){
        float pre = a1s[i][j] + b1p[i];
        hp[j] = fmaxf(pre, 0.f);
      }
      st4(&H1p[(4 * cg + i) * 4], hv);
    }
  }
  // no barrier: H1W consumed by same wave below (per-wave LDS ordering)

  // ---- phase 2: ah = h1@W2^T, at = m1^T R ; WR interleaved L2 stream ----
  v2f ah2[4][2], at2[4][2];
#pragma unroll
  for (int i = 0; i < 4; i++)
#pragma unroll
    for (int jp = 0; jp < 2; jp++){
      ah2[i][jp].x = 0.f; ah2[i][jp].y = 0.f;
      at2[i][jp].x = 0.f; at2[i][jp].y = 0.f;
    }
#pragma unroll 1
  for (int g = 0; g < 16; g++){
    f4 wc[4], rc[4];
#pragma unroll
    for (int u = 0; u < 4; u++){ wc[u] = wb[u]; rc[u] = rb[u]; }
    if (g < 15){
      const int kn = kb + (g + 1) * 4;
#pragma unroll
      for (int u = 0; u < 4; u++){
        wb[u] = WR4[(kn + u) * 64 + cg];
        rb[u] = WR4[(kn + u) * 64 + 32 + cg];
      }
    }
#pragma unroll
    for (int u = 0; u < 4; u++){
      const int k = kb + g * 4 + u;
      f4 av = ld4(&H1p[k * 4]);                     // broadcast (4 rows)
      v2f a0 = vlo(av), a1 = vhi(av);
      v2f m0, m1;                                    // mask = (h1>0), exact
      m0.x = (a0.x > 0.f) ? 1.f : 0.f; m0.y = (a0.y > 0.f) ? 1.f : 0.f;
      m1.x = (a1.x > 0.f) ? 1.f : 0.f; m1.y = (a1.y > 0.f) ? 1.f : 0.f;
      v2f wA = vlo(wc[u]), wB = vhi(wc[u]);
      v2f rA = vlo(rc[u]), rB = vhi(rc[u]);
      pk_lo(ah2[0][0], wA, a0); pk_lo(ah2[0][1], wA, a1);
      pk_hi(ah2[1][0], wA, a0); pk_hi(ah2[1][1], wA, a1);
      pk_lo(ah2[2][0], wB, a0); pk_lo(ah2[2][1], wB, a1);
      pk_hi(ah2[3][0], wB, a0); pk_hi(ah2[3][1], wB, a1);
      pk_lo(at2[0][0], rA, m0); pk_lo(at2[0][1], rA, m1);
      pk_hi(at2[1][0], rA, m0); pk_hi(at2[1][1], rA, m1);
      pk_lo(at2[2][0], rB, m0); pk_lo(at2[2][1], rB, m1);
      pk_hi(at2[3][0], rB, m0); pk_hi(at2[3][1], rB, m1);
    }
  }
  float ah[4][4], at[4][4];
#pragma unroll
  for (int i = 0; i < 4; i++){
    ah[i][0] = ah2[i][0].x; ah[i][1] = ah2[i][0].y;
    ah[i][2] = ah2[i][1].x; ah[i][3] = ah2[i][1].y;
    at[i][0] = at2[i][0].x; at[i][1] = at2[i][0].y;
    at[i][2] = at2[i][1].x; at[i][3] = at2[i][1].y;
  }
#pragma unroll
  for (int i = 0; i < 4; i++)
#pragma unroll
    for (int j = 0; j < 4; j++){
      ah[i][j] += __shfl_xor(ah[i][j], 32);
      at[i][j] += __shfl_xor(at[i][j], 32);
    }

  f4 b2v = ld4(&lds[L_B2 + 4 * cg]);
  const float* b2p = (const float*)&b2v;
  float h2v[4][4]; float dl[4] = {0.f, 0.f, 0.f, 0.f};
#pragma unroll
  for (int i = 0; i < 4; i++)
#pragma unroll
    for (int j = 0; j < 4; j++){
      float pre = ah[i][j] + b2p[i];
      float hv = fmaxf(pre, 0.f);
      h2v[i][j] = hv;
      if (pre > 0.f) dl[j] += at[i][j];
    }
#pragma unroll
  for (int mk = 1; mk < 32; mk <<= 1){
#pragma unroll
    for (int j = 0; j < 4; j++) dl[j] += __shfl_xor(dl[j], mk, 64);
  }
  if (kh == 0){
#pragma unroll
    for (int i = 0; i < 4; i++){
      f4 hv; float* hp = (float*)&hv;
#pragma unroll
      for (int j = 0; j < 4; j++) hp[j] = h2v[i][j];
      st4(&H2p[(4 * cg + i) * 4], hv);
    }
    if (cg == 0){
#pragma unroll
      for (int j = 0; j < 4; j++)
        lds[L_KL + kout * 32 + 4 * w + j] = dl[j] + trP;
    }
  }
  // no barrier: H2W consumed by same wave below

  // ---- phase 3: dz = -(h2 @ C3 + c0 + x @ P) -> KZ rows of this wave ----
  v2f a3e[2], a3o[2];
  a3e[0].x=0.f;a3e[0].y=0.f;a3e[1].x=0.f;a3e[1].y=0.f;
  a3o[0].x=0.f;a3o[0].y=0.f;a3o[1].x=0.f;a3o[1].y=0.f;
  const int bb = kh * 64;
#pragma unroll 4
  for (int t = 0; t < 16; t++){
    f4 cv = ld4(&lds[L_C3T + cg * 132 + bb + 4 * t]);
    v2f cA = vlo(cv), cB = vhi(cv);
    { f4 av = ld4(&H2p[(bb + 4 * t + 0) * 4]);
      pk_lo(a3e[0], cA, vlo(av)); pk_lo(a3e[1], cA, vhi(av)); }
    { f4 av = ld4(&H2p[(bb + 4 * t + 1) * 4]);
      pk_hi(a3o[0], cA, vlo(av)); pk_hi(a3o[1], cA, vhi(av)); }
    { f4 av = ld4(&H2p[(bb + 4 * t + 2) * 4]);
      pk_lo(a3e[0], cB, vlo(av)); pk_lo(a3e[1], cB, vhi(av)); }
    { f4 av = ld4(&H2p[(bb + 4 * t + 3) * 4]);
      pk_hi(a3o[0], cB, vhi(av) * 0.f + vlo(av)); pk_hi(a3o[1], cB, vhi(av)); }
  }
  const int qq = kh * 16;
#pragma unroll
  for (int t = 0; t < 4; t++){
    f4 pv = ld4(&lds[L_PT + cg * 36 + qq + 4 * t]);
    v2f pA = vlo(pv), pB = vhi(pv);
    { f4 av = ld4(&XWp[(qq + 4 * t + 0) * 4]);
      pk_lo(a3e[0], pA, vlo(av)); pk_lo(a3e[1], pA, vhi(av)); }
    { f4 av = ld4(&XWp[(qq + 4 * t + 1) * 4]);
      pk_hi(a3o[0], pA, vlo(av)); pk_hi(a3o[1], pA, vhi(av)); }
    { f4 av = ld4(&XWp[(qq + 4 * t + 2) * 4]);
      pk_lo(a3e[0], pB, vlo(av)); pk_lo(a3e[1], pB, vhi(av)); }
    { f4 av = ld4(&XWp[(qq + 4 * t + 3) * 4]);
      pk_hi(a3o[0], pB, vlo(av)); pk_hi(a3o[1], pB, vhi(av)); }
  }
  float a3[4];
  a3[0] = a3e[0].x + a3o[0].x; a3[1] = a3e[0].y + a3o[0].y;
  a3[2] = a3e[1].x + a3o[1].x; a3[3] = a3e[1].y + a3o[1].y;
#pragma unroll
  for (int j = 0; j < 4; j++) a3[j] += __shfl_xor(a3[j], 32);
  if (kh == 0){
    float c0v = lds[L_C0 + cg];
#pragma unroll
    for (int j = 0; j < 4; j++)
      lds[L_KZ + kout * 1152 + (4 * w + j) * 36 + cg] = -(a3[j] + c0v);
  }
}

__global__ void __launch_bounds__(NT, 2)
qpnf_kernel(const float* __restrict__ z, const float* __restrict__ Gw,
            const float* __restrict__ W1g, const float* __restrict__ b1g,
            const float* __restrict__ W2g, const float* __restrict__ b2g,
            const float* __restrict__ W3g, const float* __restrict__ b3g,
            const float* __restrict__ Tg, float* __restrict__ out,
            float* __restrict__ ws)
{
  __shared__ float lds[LDS_FLOATS];
  const int tid = threadIdx.x;
  const int bid = blockIdx.x;
  const int r0 = bid * RB;
  cg::grid_group grid = cg::this_grid();

  // ================= init =================
  for (int i = 0; i < 8; i++){                // W1T[j][h] = W1[h][j]
    int idx = tid + i * NT;
    int h = idx >> 5, j = idx & 31;
    lds[L_W1T + j * 128 + h] = W1g[idx];
  }
  if (tid < 128){ lds[L_B1 + tid] = b1g[tid]; lds[L_B2 + tid] = b2g[tid]; }
  if (tid < 256) lds[L_GS + tid] = Gw[tid];
  __syncthreads();

  if (tid < 64){                              // A = G G^T (8x8), augmented
    int i = tid >> 3, j = tid & 7;
    float s = 0.f;
    for (int k = 0; k < 32; k++) s += lds[L_GS + i * 32 + k] * lds[L_GS + j * 32 + k];
    lds[L_AAUG + i * 16 + j] = s;
    lds[L_AAUG + i * 16 + 8 + j] = (i == j) ? 1.f : 0.f;
  }
  __syncthreads();
  if (tid == 0){                              // Gauss-Jordan, partial pivoting
    float* A = &lds[L_AAUG];
    for (int c = 0; c < 8; c++){
      int p = c; float mx = fabsf(A[c * 16 + c]);
      for (int r = c + 1; r < 8; r++){
        float v = fabsf(A[r * 16 + c]);
        if (v > mx){ mx = v; p = r; }
      }
      if (p != c)
        for (int q = 0; q < 16; q++){ float t = A[c*16+q]; A[c*16+q] = A[p*16+q]; A[p*16+q] = t; }
      float pv = 1.0f / A[c * 16 + c];
      for (int q = 0; q < 16; q++) A[c * 16 + q] *= pv;
      for (int r = 0; r < 8; r++) if (r != c){
        float fct = A[r * 16 + c];
        for (int q = 0; q < 16; q++) A[r * 16 + q] -= fct * A[c * 16 + q];
      }
    }
  }
  __syncthreads();
  if (tid < 256){                              // AinvG[m][d]
    int m = tid >> 5, d = tid & 31;
    float s = 0.f;
    for (int q = 0; q < 8; q++) s += lds[L_AAUG + m * 16 + 8 + q] * lds[L_GS + q * 32 + d];
    lds[L_AINVG + m * 32 + d] = s;
  }
  __syncthreads();
  for (int i4 = 0; i4 < 2; i4++){              // P = G^T AinvG (alias in H2W)
    int idx = tid + i4 * NT;
    int i = idx >> 5, j = idx & 31;
    float s = 0.f;
    for (int m = 0; m < 8; m++) s += lds[L_GS + m * 32 + i] * lds[L_AINVG + m * 32 + j];
    lds[L_P + i * 32 + j] = s;
  }
  __syncthreads();
  float* IPl = &lds[L_IP];                     // IP aliases H2W+1024 during init
  for (int i4 = 0; i4 < 2; i4++){
    int idx = tid + i4 * NT;
    int i = idx >> 5, j = idx & 31;
    IPl[i * 32 + j] = ((i == j) ? 1.f : 0.f) - lds[L_P + i * 32 + j];
  }
  if (tid == 0){
    float s = 0.f;
    for (int i = 0; i < 32; i++) s += lds[L_P + i * 32 + i];
    lds[L_MISC] = s;                           // trP
  }
  __syncthreads();
  for (int i4 = 0; i4 < 8; i4++){              // C3T[c][b] = sum_i W3[i][b] IP[i][c]
    int idx = tid + i4 * NT;
    int b = idx & 127, c = idx >> 7;
    float s = 0.f;
    for (int i = 0; i < 32; i++) s += W3g[i * 128 + b] * IPl[i * 32 + c];
    lds[L_C3T + c * 132 + b] = s;
  }
  for (int i4 = 0; i4 < 2; i4++){              // PT[c][q] = P[q][c]
    int idx = tid + i4 * NT;
    int c = idx >> 5, q = idx & 31;
    lds[L_PT + c * 36 + q] = lds[L_P + q * 32 + c];
  }
  if (tid < 32){                               // c0 = b3 @ IP
    float s = 0.f;
    for (int i = 0; i < 32; i++) s += b3g[i] * IPl[i * 32 + tid];
    lds[L_C0 + tid] = s;
  }
  for (int i4 = 0; i4 < 8; i4++){              // IPW3[j][b] (aliases KZ)
    int idx = tid + i4 * NT;
    int j = idx >> 7, b = idx & 127;
    float s = 0.f;
    for (int k = 0; k < 32; k++) s += IPl[j * 32 + k] * W3g[k * 128 + b];
    lds[L_IPW3 + j * 128 + b] = s;
  }
  __syncthreads();
  if (bid < 128 && tid < 128){                 // R row a=bid -> WR[a][128+b]
    int a = bid;
    float s = 0.f;
    for (int j = 0; j < 32; j++) s += W1g[a * 32 + j] * lds[L_IPW3 + j * 128 + tid];
    ws[WS_WR + a * 256 + 128 + tid] = s * W2g[tid * 128 + a];
  }
  if (bid >= 128 && tid < 128){                // W2T row a -> WR[a][b]
    int a = bid - 128;
    ws[WS_WR + a * 256 + tid] = W2g[tid * 128 + a];
  }
  if (tid < 256){                              // y0 = [z, 0] -> LDS
    const int r = tid >> 3, jj = (tid & 7) * 4;
    st4(&lds[L_YZ + r * 36 + jj], ld4(&z[(r0 + r) * 32 + jj]));
  }
  if (tid < RB) lds[L_YL + tid] = 0.f;

  const float trP = lds[L_MISC];
  const float t1 = 2.0f * Tg[0];

  grid.sync();

  // ================= main adaptive RK loop =================
  float t_cur = 0.f, dt_cur = 0.25f;
  bool prev_acc = false;

  for (int step = 0; step < 10; step++){
    if (t_cur >= t1 - 1e-9f) break;            // uniform across grid
    const float dtc = fminf(dt_cur, t1 - t_cur);

    // stages 1..6 — fully wave-local, NO barriers: waves free-run and skew
    for (int s = 1; s <= 6; s++){
      if (s == 1 && step > 0){
        if (prev_acc){                         // FSAL: k1 = previous k7 (wave-local)
          const int w = tid >> 6, lane = tid & 63;
          const int r = lane >> 4, c = (lane << 1) & 31;
          const int o = (4 * w + r) * 36 + c;
          *(f2*)&lds[L_KZ + o] = *(const f2*)&lds[L_KZ + 6 * 1152 + o];
          if (lane < 4) lds[L_KL + 4 * w + lane] = lds[L_KL + 6 * 32 + 4 * w + lane];
        }                                       // rejected: k1 = f(y) unchanged
        continue;
      }
      assemble_x(lds, tid, dtc, ACO[s >= 2 ? s - 2 : 0], s - 1);
      eval_f(lds, ws, tid, trP, s - 1);
    }

    // stage 7: y1, k7 = f(y1), error estimate
    __syncthreads();                           // all waves' KZ/KL visible
    if (tid < 256){
      const int r = tid >> 3, jj = (tid & 7) * 4;
      const int o = r * 36 + jj;
      f4 y   = ld4(&lds[L_YZ + o]);
      f4 k1v = ld4(&lds[L_KZ + 0 * 1152 + o]);
      f4 k3v = ld4(&lds[L_KZ + 2 * 1152 + o]);
      f4 k4v = ld4(&lds[L_KZ + 3 * 1152 + o]);
      f4 k5v = ld4(&lds[L_KZ + 4 * 1152 + o]);
      f4 k6v = ld4(&lds[L_KZ + 5 * 1152 + o]);
      f4 x;
      x.x = y.x + dtc * (B1C*k1v.x + B3C*k3v.x + B4C*k4v.x + B5C*k5v.x + B6C*k6v.x);
      x.y = y.y + dtc * (B1C*k1v.y + B3C*k3v.y + B4C*k4v.y + B5C*k5v.y + B6C*k6v.y);
      x.z = y.z + dtc * (B1C*k1v.z + B3C*k3v.z + B4C*k4v.z + B5C*k5v.z + B6C*k6v.z);
      x.w = y.w + dtc * (B1C*k1v.w + B3C*k3v.w + B4C*k4v.w + B5C*k5v.w + B6C*k6v.w);
      st4(&lds[L_Y1Z + o], x);
      float* XWp = &lds[L_XW + (r >> 2) * 128];   // scatter into owning wave's XW
      const int rr = r & 3;
      XWp[(jj + 0) * 4 + rr] = x.x;
      XWp[(jj + 1) * 4 + rr] = x.y;
      XWp[(jj + 2) * 4 + rr] = x.z;
      XWp[(jj + 3) * 4 + rr] = x.w;
    }
    if (tid < RB){
      float s = B1C * lds[L_KL + 0*32 + tid] + B3C * lds[L_KL + 2*32 + tid]
              + B4C * lds[L_KL + 3*32 + tid] + B5C * lds[L_KL + 4*32 + tid]
              + B6C * lds[L_KL + 5*32 + tid];
      lds[L_Y1L + tid] = lds[L_YL + tid] + dtc * s;
    }
    __syncthreads();                           // XW scatter was cross-wave
    eval_f(lds, ws, tid, trP, 6);
    __syncthreads();                           // all waves' k7 visible

    float sacc = 0.f;
    if (tid < 256){
      const int r = tid >> 3, jj = (tid & 7) * 4;
      const int o = r * 36 + jj;
      f4 k1v = ld4(&lds[L_KZ + 0 * 1152 + o]);
      f4 k3v = ld4(&lds[L_KZ + 2 * 1152 + o]);
      f4 k4v = ld4(&lds[L_KZ + 3 * 1152 + o]);
      f4 k5v = ld4(&lds[L_KZ + 4 * 1152 + o]);
      f4 k6v = ld4(&lds[L_KZ + 5 * 1152 + o]);
      f4 k7v = ld4(&lds[L_KZ + 6 * 1152 + o]);
      f4 yv  = ld4(&lds[L_YZ + o]);
      f4 y1v = ld4(&lds[L_Y1Z + o]);
      float ev, tol, q;
      ev = dtc * (E1C*k1v.x + E3C*k3v.x + E4C*k4v.x + E5C*k5v.x + E6C*k6v.x + E7C*k7v.x);
      tol = 1e-5f + 1e-5f * fmaxf(fabsf(yv.x), fabsf(y1v.x)); q = ev / tol; sacc += q * q;
      ev = dtc * (E1C*k1v.y + E3C*k3v.y + E4C*k4v.y + E5C*k5v.y + E6C*k6v.y + E7C*k7v.y);
      tol = 1e-5f + 1e-5f * fmaxf(fabsf(yv.y), fabsf(y1v.y)); q = ev / tol; sacc += q * q;
      ev = dtc * (E1C*k1v.z + E3C*k3v.z + E4C*k4v.z + E5C*k5v.z + E6C*k6v.z + E7C*k7v.z);
      tol = 1e-5f + 1e-5f * fmaxf(fabsf(yv.z), fabsf(y1v.z)); q = ev / tol; sacc += q * q;
      ev = dtc * (E1C*k1v.w + E3C*k3v.w + E4C*k4v.w + E5C*k5v.w + E6C*k6v.w + E7C*k7v.w);
      tol = 1e-5f + 1e-5f * fmaxf(fabsf(yv.w), fabsf(y1v.w)); q = ev / tol; sacc += q * q;
    }
    if (tid < RB){
      float evl = dtc * (E1C * lds[L_KL + 0*32 + tid] + E3C * lds[L_KL + 2*32 + tid]
                + E4C * lds[L_KL + 3*32 + tid] + E5C * lds[L_KL + 4*32 + tid]
                + E6C * lds[L_KL + 5*32 + tid] + E7C * lds[L_KL + 6*32 + tid]);
      float toll = 1e-5f + 1e-5f * fmaxf(fabsf(lds[L_YL + tid]), fabsf(lds[L_Y1L + tid]));
      float ql = evl / toll; sacc += ql * ql;
    }
    // block reduction: wave butterflies + 8-wide LDS combine
#pragma unroll
    for (int mk = 1; mk < 64; mk <<= 1) sacc += __shfl_xor(sacc, mk, 64);
    if ((tid & 63) == 0) lds[L_RED + (tid >> 6)] = sacc;   // RED aliases dead H1W
    __syncthreads();
    if (tid == 0){
      float s = lds[L_RED+0] + lds[L_RED+1] + lds[L_RED+2] + lds[L_RED+3]
              + lds[L_RED+4] + lds[L_RED+5] + lds[L_RED+6] + lds[L_RED+7];
      ws[WS_PART + step * 256 + bid] = s;
    }

    grid.sync();

    // deterministic global reduction (every block, identical order)
    float ps = 0.f;
    if (tid < 256) ps = ws[WS_PART + step * 256 + tid];
#pragma unroll
    for (int mk = 1; mk < 64; mk <<= 1) ps += __shfl_xor(ps, mk, 64);
    if (tid < 256 && (tid & 63) == 0) lds[L_RED + (tid >> 6)] = ps;
    __syncthreads();
    const float errn = sqrtf((lds[L_RED+0] + lds[L_RED+1] + lds[L_RED+2] + lds[L_RED+3])
                             / 270336.0f);
    __syncthreads();             // protect RED(=H1W) before next phase-1 overwrite

    const bool accept = (errn <= 1.0f);
    if (accept){                               // wave-local y <- y1
      const int w = tid >> 6, lane = tid & 63;
      const int r = lane >> 4, c = (lane << 1) & 31;
      const int o = (4 * w + r) * 36 + c;
      *(f2*)&lds[L_YZ + o] = *(const f2*)&lds[L_Y1Z + o];
      if (lane < 4) lds[L_YL + 4 * w + lane] = lds[L_Y1L + 4 * w + lane];
      t_cur += dtc;
    }
    float fac = 0.9f * powf(errn, -0.2f);
    fac = fminf(fmaxf(fac, 0.2f), 10.0f);
    dt_cur = fminf(fmaxf(dtc * fac, 1e-6f), t1);
    prev_acc = accept;
  }

  // ---- output: yT[:, :d] ----
  __syncthreads();
  if (tid < 256){
    const int r = tid >> 3, jj = (tid & 7) * 4;
    st4(&out[(r0 + r) * 32 + jj], ld4(&lds[L_YZ + r * 36 + jj]));
  }
}

extern "C" void kernel_launch(void* const* d_in, const int* in_sizes, int n_in,
                              void* d_out, int out_size, void* d_ws, size_t ws_size,
                              hipStream_t stream)
{
  (void)in_sizes; (void)n_in; (void)out_size;
  const float* z  = (const float*)d_in[0];
  const float* Gw = (const float*)d_in[1];
  const float* W1 = (const float*)d_in[2];
  const float* b1 = (const float*)d_in[3];
  const float* W2 = (const float*)d_in[4];
  const float* b2 = (const float*)d_in[5];
  const float* W3 = (const float*)d_in[6];
  const float* b3 = (const float*)d_in[7];
  const float* T  = (const float*)d_in[8];
  float* out = (float*)d_out;
  float* ws  = (float*)d_ws;
  if (ws_size < (size_t)WS_TOTAL * sizeof(float)) return;

  void* args[] = { (void*)&z, (void*)&Gw, (void*)&W1, (void*)&b1, (void*)&W2,
                   (void*)&b2, (void*)&W3, (void*)&b3, (void*)&T, (void*)&out,
                   (void*)&ws };
  hipLaunchCooperativeKernel((const void*)qpnf_kernel, dim3(256), dim3(NT),
                             args, 0, stream);
}

// Round 10
// 1181.219 us; speedup vs baseline: 1.1774x; 1.0467x over previous
//
#include <hip/hip_runtime.h>
#include <hip/hip_cooperative_groups.h>
#include <math.h>

namespace cg = cooperative_groups;
typedef float4 f4;
typedef float2 f2;

#define NT 512          // 8 waves/block; wave-local dataflow: wave w owns rows 4w..4w+3
#define RB 32           // rows per block; GRID=256 (cooperative cap)

// ---------------- workspace float offsets (weights + partials only) -------
#define WS_WR    0          // WR[128][256]: [k][0:128]=W2T row k, [k][128:256]=R row k
#define WS_PART  32768      // [10][256] err partials
#define WS_TOTAL 35328

// ---------------- LDS float offsets (118.3 KB) ----------------------------
#define L_W1T   0           // [32][128]  W1T[j][h] = W1[h][j]
#define L_C3T   4096        // [32][132]  C3T[c][b] = C3[b][c]
#define L_PT    8320        // [32][36]   PT[c][q] = P[q][c]
#define L_XW    9472        // [8][32][4]  per-wave x, k-major: XW[w][k][r]
#define L_H1W   10496       // [8][128][4] per-wave h1, h-major: H1W[w][h][r]
#define L_H2W   14592       // [8][128][4] per-wave h2
#define L_KZ    18688       // [7][32][36] k_z, pitch 36
#define L_KL    26752       // [7][32]     k_l
#define L_YZ    26976       // [32][36]    y_z
#define L_Y1Z   28128       // [32][36]    y1_z
#define L_YL    29280       // [32]
#define L_Y1L   29312       // [32]
#define L_B1    29344
#define L_B2    29472
#define L_C0    29600
#define L_GS    29632       // [8][32]
#define L_AAUG  29888       // [8][16]
#define L_AINVG 30016       // [8][32]
#define L_MISC  30272       // [0]=trP
#define LDS_FLOATS 30276
#define L_RED   L_H1W       // [8] alias — H1W dead during error reduction
#define L_P     L_H2W       // [32][32] init-only alias
#define L_IP    (L_H2W + 1024) // [32][32] init-only alias
#define L_IPW3  L_KZ        // [32][128] init-only alias

__device__ const float ACO[5][5] = {
  { 0.2f, 0.f, 0.f, 0.f, 0.f },
  { (float)(3.0/40.0), (float)(9.0/40.0), 0.f, 0.f, 0.f },
  { (float)(44.0/45.0), (float)(-56.0/15.0), (float)(32.0/9.0), 0.f, 0.f },
  { (float)(19372.0/6561.0), (float)(-25360.0/2187.0), (float)(64448.0/6561.0), (float)(-212.0/729.0), 0.f },
  { (float)(9017.0/3168.0), (float)(-355.0/33.0), (float)(46732.0/5247.0), (float)(49.0/176.0), (float)(-5103.0/18656.0) }
};

#define B1C ((float)(35.0/384.0))
#define B3C ((float)(500.0/1113.0))
#define B4C ((float)(125.0/192.0))
#define B5C ((float)(-2187.0/6784.0))
#define B6C ((float)(11.0/84.0))

#define E1C ((float)(35.0/384.0 - 5179.0/57600.0))
#define E3C ((float)(500.0/1113.0 - 7571.0/16695.0))
#define E4C ((float)(125.0/192.0 - 393.0/640.0))
#define E5C ((float)(-2187.0/6784.0 + 92097.0/339200.0))
#define E6C ((float)(11.0/84.0 - 187.0/2100.0))
#define E7C ((float)(-1.0/40.0))

__device__ __forceinline__ f4 ld4(const float* p){ return *(const f4*)p; }
__device__ __forceinline__ void st4(float* p, f4 v){ *(f4*)p = v; }

// wave-local assemble: x = y + dtc*sum_p co[p]*k[p] -> XW[w] (k-major).
// No barriers: KZ rows 4w..4w+3 were written by this wave, XW read by this wave.
__device__ __forceinline__ void assemble_x(float* lds, int tid, float dtc,
                                           const float* co, int np)
{
  const int w = tid >> 6, lane = tid & 63;
  const int r = lane >> 4;            // 0..3 local row
  const int c = (lane << 1) & 31;     // even col
  const int o = (4 * w + r) * 36 + c;
  f2 y = *(const f2*)&lds[L_YZ + o];
  float sx = 0.f, sy = 0.f;
  for (int p = 0; p < np; p++){
    f2 kv = *(const f2*)&lds[L_KZ + p * 1152 + o];
    sx += co[p] * kv.x; sy += co[p] * kv.y;
  }
  float* XWp = &lds[L_XW + w * 128];
  XWp[(c + 0) * 4 + r] = y.x + dtc * sx;
  XWp[(c + 1) * 4 + r] = y.y + dtc * sy;
}

// full f-eval, wave-local: XW[w] -> KZ rows 4w..4w+3, KL rows 4w..4w+3.
// ZERO barriers: all phases are own-wave data (same-wave LDS ds ops are
// ordered by HW; cross-lane register returns get compiler waitcnts).
// Waves free-run and skew across stages -> VMEM stream of one wave
// overlaps VALU phases of others on the same SIMD.
__device__ void eval_f(float* lds, const float* __restrict__ ws, int tid,
                       float trP, int kout)
{
  const int w = tid >> 6, lane = tid & 63;
  const int cg = lane & 31, kh = lane >> 5;
  float* XWp = &lds[L_XW  + w * 128];
  float* H1p = &lds[L_H1W + w * 512];
  float* H2p = &lds[L_H2W + w * 512];

  // ---- issue first WR prefetch NOW: L2 latency hides under phase 1 ----
  const f4* WR4 = (const f4*)&ws[WS_WR];   // row k = 64 f4: [0:32)=W2T, [32:64)=R
  const int kb = kh * 64;
  f4 wb[4], rb[4];
#pragma unroll
  for (int u = 0; u < 4; u++){
    wb[u] = WR4[(kb + u) * 64 + cg];
    rb[u] = WR4[(kb + u) * 64 + 32 + cg];
  }

  // ---- phase 1: h1 = relu(x @ W1^T + b1) -> H1W[w] ; k split over halves ----
  float a1[4][4];
#pragma unroll
  for (int i = 0; i < 4; i++)
#pragma unroll
    for (int j = 0; j < 4; j++) a1[i][j] = 0.f;
#pragma unroll 4
  for (int t = 0; t < 16; t++){
    const int k = kh * 16 + t;
    f4 xv = ld4(&XWp[k * 4]);                       // broadcast (4 rows)
    f4 wv = ld4(&lds[L_W1T + k * 128 + 4 * cg]);
    const float* ap = (const float*)&xv;
    const float* bp = (const float*)&wv;
#pragma unroll
    for (int i = 0; i < 4; i++)
#pragma unroll
      for (int j = 0; j < 4; j++) a1[i][j] += bp[i] * ap[j];
  }
#pragma unroll
  for (int i = 0; i < 4; i++)
#pragma unroll
    for (int j = 0; j < 4; j++) a1[i][j] += __shfl_xor(a1[i][j], 32);
  if (kh == 0){
    f4 b1v = ld4(&lds[L_B1 + 4 * cg]);
    const float* b1p = (const float*)&b1v;
#pragma unroll
    for (int i = 0; i < 4; i++){
      f4 hv; float* hp = (float*)&hv;
#pragma unroll
      for (int j = 0; j < 4; j++) hp[j] = fmaxf(a1[i][j] + b1p[i], 0.f);
      st4(&H1p[(4 * cg + i) * 4], hv);
    }
  }
  // no barrier: H1W[w] consumed by same wave below (per-wave LDS ordering)

  // ---- phase 2: ah = h1@W2^T, at = m1^T R ; WR interleaved L2 stream ----
  float ah[4][4], at[4][4];
#pragma unroll
  for (int i = 0; i < 4; i++)
#pragma unroll
    for (int j = 0; j < 4; j++){ ah[i][j] = 0.f; at[i][j] = 0.f; }
#pragma unroll 1
  for (int g = 0; g < 16; g++){
    f4 wc[4], rc[4];
#pragma unroll
    for (int u = 0; u < 4; u++){ wc[u] = wb[u]; rc[u] = rb[u]; }
    if (g < 15){
      const int kn = kb + (g + 1) * 4;
#pragma unroll
      for (int u = 0; u < 4; u++){
        wb[u] = WR4[(kn + u) * 64 + cg];
        rb[u] = WR4[(kn + u) * 64 + 32 + cg];
      }
    }
#pragma unroll
    for (int u = 0; u < 4; u++){
      const int k = kb + g * 4 + u;
      f4 av = ld4(&H1p[k * 4]);                     // broadcast (4 rows)
      const float* ap = (const float*)&av;
      const float* wp = (const float*)&wc[u];
      const float* rp = (const float*)&rc[u];
      float m[4];
#pragma unroll
      for (int j = 0; j < 4; j++) m[j] = (ap[j] > 0.f) ? 1.f : 0.f;
#pragma unroll
      for (int i = 0; i < 4; i++)
#pragma unroll
        for (int j = 0; j < 4; j++){
          ah[i][j] += wp[i] * ap[j];
          at[i][j] += rp[i] * m[j];
        }
    }
  }
#pragma unroll
  for (int i = 0; i < 4; i++)
#pragma unroll
    for (int j = 0; j < 4; j++){
      ah[i][j] += __shfl_xor(ah[i][j], 32);
      at[i][j] += __shfl_xor(at[i][j], 32);
    }

  f4 b2v = ld4(&lds[L_B2 + 4 * cg]);
  const float* b2p = (const float*)&b2v;
  float h2v[4][4]; float dl[4] = {0.f, 0.f, 0.f, 0.f};
#pragma unroll
  for (int i = 0; i < 4; i++)
#pragma unroll
    for (int j = 0; j < 4; j++){
      float pre = ah[i][j] + b2p[i];
      float hv = fmaxf(pre, 0.f);
      h2v[i][j] = hv;
      if (pre > 0.f) dl[j] += at[i][j];
    }
#pragma unroll
  for (int mk = 1; mk < 32; mk <<= 1){
#pragma unroll
    for (int j = 0; j < 4; j++) dl[j] += __shfl_xor(dl[j], mk, 64);
  }
  if (kh == 0){
#pragma unroll
    for (int i = 0; i < 4; i++){
      f4 hv; float* hp = (float*)&hv;
#pragma unroll
      for (int j = 0; j < 4; j++) hp[j] = h2v[i][j];
      st4(&H2p[(4 * cg + i) * 4], hv);
    }
    if (cg == 0){
#pragma unroll
      for (int j = 0; j < 4; j++)
        lds[L_KL + kout * 32 + 4 * w + j] = dl[j] + trP;
    }
  }
  // no barrier: H2W[w] consumed by same wave below

  // ---- phase 3: dz = -(h2 @ C3 + c0 + x @ P) -> KZ rows of this wave ----
  float a3[4] = {0.f, 0.f, 0.f, 0.f};
  const int bb = kh * 64;
#pragma unroll 4
  for (int t = 0; t < 16; t++){
    f4 cv = ld4(&lds[L_C3T + cg * 132 + bb + 4 * t]);
    const float* cp = (const float*)&cv;
#pragma unroll
    for (int u = 0; u < 4; u++){
      f4 av = ld4(&H2p[(bb + 4 * t + u) * 4]);      // broadcast
      const float* ap = (const float*)&av;
#pragma unroll
      for (int j = 0; j < 4; j++) a3[j] += ap[j] * cp[u];
    }
  }
  const int qq = kh * 16;
#pragma unroll
  for (int t = 0; t < 4; t++){
    f4 pv = ld4(&lds[L_PT + cg * 36 + qq + 4 * t]);
    const float* pp = (const float*)&pv;
#pragma unroll
    for (int u = 0; u < 4; u++){
      f4 av = ld4(&XWp[(qq + 4 * t + u) * 4]);      // broadcast
      const float* ap = (const float*)&av;
#pragma unroll
      for (int j = 0; j < 4; j++) a3[j] += ap[j] * pp[u];
    }
  }
#pragma unroll
  for (int j = 0; j < 4; j++) a3[j] += __shfl_xor(a3[j], 32);
  if (kh == 0){
    float c0v = lds[L_C0 + cg];
#pragma unroll
    for (int j = 0; j < 4; j++)
      lds[L_KZ + kout * 1152 + (4 * w + j) * 36 + cg] = -(a3[j] + c0v);
  }
}

__global__ void __launch_bounds__(NT, 2)
qpnf_kernel(const float* __restrict__ z, const float* __restrict__ Gw,
            const float* __restrict__ W1g, const float* __restrict__ b1g,
            const float* __restrict__ W2g, const float* __restrict__ b2g,
            const float* __restrict__ W3g, const float* __restrict__ b3g,
            const float* __restrict__ Tg, float* __restrict__ out,
            float* __restrict__ ws)
{
  __shared__ float lds[LDS_FLOATS];
  const int tid = threadIdx.x;
  const int bid = blockIdx.x;
  const int r0 = bid * RB;
  cg::grid_group grid = cg::this_grid();

  // ================= init =================
  for (int i = 0; i < 8; i++){                // W1T[j][h] = W1[h][j]
    int idx = tid + i * NT;
    int h = idx >> 5, j = idx & 31;
    lds[L_W1T + j * 128 + h] = W1g[idx];
  }
  if (tid < 128){ lds[L_B1 + tid] = b1g[tid]; lds[L_B2 + tid] = b2g[tid]; }
  if (tid < 256) lds[L_GS + tid] = Gw[tid];
  __syncthreads();

  if (tid < 64){                              // A = G G^T (8x8), augmented
    int i = tid >> 3, j = tid & 7;
    float s = 0.f;
    for (int k = 0; k < 32; k++) s += lds[L_GS + i * 32 + k] * lds[L_GS + j * 32 + k];
    lds[L_AAUG + i * 16 + j] = s;
    lds[L_AAUG + i * 16 + 8 + j] = (i == j) ? 1.f : 0.f;
  }
  __syncthreads();
  if (tid == 0){                              // Gauss-Jordan, partial pivoting
    float* A = &lds[L_AAUG];
    for (int c = 0; c < 8; c++){
      int p = c; float mx = fabsf(A[c * 16 + c]);
      for (int r = c + 1; r < 8; r++){
        float v = fabsf(A[r * 16 + c]);
        if (v > mx){ mx = v; p = r; }
      }
      if (p != c)
        for (int q = 0; q < 16; q++){ float t = A[c*16+q]; A[c*16+q] = A[p*16+q]; A[p*16+q] = t; }
      float pv = 1.0f / A[c * 16 + c];
      for (int q = 0; q < 16; q++) A[c * 16 + q] *= pv;
      for (int r = 0; r < 8; r++) if (r != c){
        float fct = A[r * 16 + c];
        for (int q = 0; q < 16; q++) A[r * 16 + q] -= fct * A[c * 16 + q];
      }
    }
  }
  __syncthreads();
  if (tid < 256){                              // AinvG[m][d]
    int m = tid >> 5, d = tid & 31;
    float s = 0.f;
    for (int q = 0; q < 8; q++) s += lds[L_AAUG + m * 16 + 8 + q] * lds[L_GS + q * 32 + d];
    lds[L_AINVG + m * 32 + d] = s;
  }
  __syncthreads();
  for (int i4 = 0; i4 < 2; i4++){              // P = G^T AinvG (alias in H2W)
    int idx = tid + i4 * NT;
    int i = idx >> 5, j = idx & 31;
    float s = 0.f;
    for (int m = 0; m < 8; m++) s += lds[L_GS + m * 32 + i] * lds[L_AINVG + m * 32 + j];
    lds[L_P + i * 32 + j] = s;
  }
  __syncthreads();
  float* IPl = &lds[L_IP];                     // IP aliases H2W+1024 during init
  for (int i4 = 0; i4 < 2; i4++){
    int idx = tid + i4 * NT;
    int i = idx >> 5, j = idx & 31;
    IPl[i * 32 + j] = ((i == j) ? 1.f : 0.f) - lds[L_P + i * 32 + j];
  }
  if (tid == 0){
    float s = 0.f;
    for (int i = 0; i < 32; i++) s += lds[L_P + i * 32 + i];
    lds[L_MISC] = s;                           // trP
  }
  __syncthreads();
  for (int i4 = 0; i4 < 8; i4++){              // C3T[c][b] = sum_i W3[i][b] IP[i][c]
    int idx = tid + i4 * NT;
    int b = idx & 127, c = idx >> 7;
    float s = 0.f;
    for (int i = 0; i < 32; i++) s += W3g[i * 128 + b] * IPl[i * 32 + c];
    lds[L_C3T + c * 132 + b] = s;
  }
  for (int i4 = 0; i4 < 2; i4++){              // PT[c][q] = P[q][c]
    int idx = tid + i4 * NT;
    int c = idx >> 5, q = idx & 31;
    lds[L_PT + c * 36 + q] = lds[L_P + q * 32 + c];
  }
  if (tid < 32){                               // c0 = b3 @ IP
    float s = 0.f;
    for (int i = 0; i < 32; i++) s += b3g[i] * IPl[i * 32 + tid];
    lds[L_C0 + tid] = s;
  }
  for (int i4 = 0; i4 < 8; i4++){              // IPW3[j][b] (aliases KZ)
    int idx = tid + i4 * NT;
    int j = idx >> 7, b = idx & 127;
    float s = 0.f;
    for (int k = 0; k < 32; k++) s += IPl[j * 32 + k] * W3g[k * 128 + b];
    lds[L_IPW3 + j * 128 + b] = s;
  }
  __syncthreads();
  if (bid < 128 && tid < 128){                 // R row a=bid -> WR[a][128+b]
    int a = bid;
    float s = 0.f;
    for (int j = 0; j < 32; j++) s += W1g[a * 32 + j] * lds[L_IPW3 + j * 128 + tid];
    ws[WS_WR + a * 256 + 128 + tid] = s * W2g[tid * 128 + a];
  }
  if (bid >= 128 && tid < 128){                // W2T row a -> WR[a][b]
    int a = bid - 128;
    ws[WS_WR + a * 256 + tid] = W2g[tid * 128 + a];
  }
  if (tid < 256){                              // y0 = [z, 0] -> LDS
    const int r = tid >> 3, jj = (tid & 7) * 4;
    st4(&lds[L_YZ + r * 36 + jj], ld4(&z[(r0 + r) * 32 + jj]));
  }
  if (tid < RB) lds[L_YL + tid] = 0.f;

  const float trP = lds[L_MISC];
  const float t1 = 2.0f * Tg[0];

  grid.sync();

  // ================= main adaptive RK loop =================
  float t_cur = 0.f, dt_cur = 0.25f;
  bool prev_acc = false;

  for (int step = 0; step < 10; step++){
    if (t_cur >= t1 - 1e-9f) break;            // uniform across grid
    const float dtc = fminf(dt_cur, t1 - t_cur);

    // stages 1..6 — fully wave-local, NO barriers: waves free-run and skew
    for (int s = 1; s <= 6; s++){
      if (s == 1 && step > 0){
        if (prev_acc){                         // FSAL: k1 = previous k7 (wave-local)
          const int w = tid >> 6, lane = tid & 63;
          const int r = lane >> 4, c = (lane << 1) & 31;
          const int o = (4 * w + r) * 36 + c;
          *(f2*)&lds[L_KZ + o] = *(const f2*)&lds[L_KZ + 6 * 1152 + o];
          if (lane < 4) lds[L_KL + 4 * w + lane] = lds[L_KL + 6 * 32 + 4 * w + lane];
        }                                       // rejected: k1 = f(y) unchanged
        continue;
      }
      assemble_x(lds, tid, dtc, ACO[s >= 2 ? s - 2 : 0], s - 1);
      eval_f(lds, ws, tid, trP, s - 1);
    }

    // stage 7: y1, k7 = f(y1), error estimate
    __syncthreads();                           // all waves' KZ/KL visible
    if (tid < 256){
      const int r = tid >> 3, jj = (tid & 7) * 4;
      const int o = r * 36 + jj;
      f4 y   = ld4(&lds[L_YZ + o]);
      f4 k1v = ld4(&lds[L_KZ + 0 * 1152 + o]);
      f4 k3v = ld4(&lds[L_KZ + 2 * 1152 + o]);
      f4 k4v = ld4(&lds[L_KZ + 3 * 1152 + o]);
      f4 k5v = ld4(&lds[L_KZ + 4 * 1152 + o]);
      f4 k6v = ld4(&lds[L_KZ + 5 * 1152 + o]);
      f4 x;
      x.x = y.x + dtc * (B1C*k1v.x + B3C*k3v.x + B4C*k4v.x + B5C*k5v.x + B6C*k6v.x);
      x.y = y.y + dtc * (B1C*k1v.y + B3C*k3v.y + B4C*k4v.y + B5C*k5v.y + B6C*k6v.y);
      x.z = y.z + dtc * (B1C*k1v.z + B3C*k3v.z + B4C*k4v.z + B5C*k5v.z + B6C*k6v.z);
      x.w = y.w + dtc * (B1C*k1v.w + B3C*k3v.w + B4C*k4v.w + B5C*k5v.w + B6C*k6v.w);
      st4(&lds[L_Y1Z + o], x);
      float* XWp = &lds[L_XW + (r >> 2) * 128];   // scatter into owning wave's XW
      const int rr = r & 3;
      XWp[(jj + 0) * 4 + rr] = x.x;
      XWp[(jj + 1) * 4 + rr] = x.y;
      XWp[(jj + 2) * 4 + rr] = x.z;
      XWp[(jj + 3) * 4 + rr] = x.w;
    }
    if (tid < RB){
      float s = B1C * lds[L_KL + 0*32 + tid] + B3C * lds[L_KL + 2*32 + tid]
              + B4C * lds[L_KL + 3*32 + tid] + B5C * lds[L_KL + 4*32 + tid]
              + B6C * lds[L_KL + 5*32 + tid];
      lds[L_Y1L + tid] = lds[L_YL + tid] + dtc * s;
    }
    __syncthreads();                           // XW scatter was cross-wave
    eval_f(lds, ws, tid, trP, 6);
    __syncthreads();                           // all waves' k7 visible

    float sacc = 0.f;
    if (tid < 256){
      const int r = tid >> 3, jj = (tid & 7) * 4;
      const int o = r * 36 + jj;
      f4 k1v = ld4(&lds[L_KZ + 0 * 1152 + o]);
      f4 k3v = ld4(&lds[L_KZ + 2 * 1152 + o]);
      f4 k4v = ld4(&lds[L_KZ + 3 * 1152 + o]);
      f4 k5v = ld4(&lds[L_KZ + 4 * 1152 + o]);
      f4 k6v = ld4(&lds[L_KZ + 5 * 1152 + o]);
      f4 k7v = ld4(&lds[L_KZ + 6 * 1152 + o]);
      f4 yv  = ld4(&lds[L_YZ + o]);
      f4 y1v = ld4(&lds[L_Y1Z + o]);
      float ev, tol, q;
      ev = dtc * (E1C*k1v.x + E3C*k3v.x + E4C*k4v.x + E5C*k5v.x + E6C*k6v.x + E7C*k7v.x);
      tol = 1e-5f + 1e-5f * fmaxf(fabsf(yv.x), fabsf(y1v.x)); q = ev / tol; sacc += q * q;
      ev = dtc * (E1C*k1v.y + E3C*k3v.y + E4C*k4v.y + E5C*k5v.y + E6C*k6v.y + E7C*k7v.y);
      tol = 1e-5f + 1e-5f * fmaxf(fabsf(yv.y), fabsf(y1v.y)); q = ev / tol; sacc += q * q;
      ev = dtc * (E1C*k1v.z + E3C*k3v.z + E4C*k4v.z + E5C*k5v.z + E6C*k6v.z + E7C*k7v.z);
      tol = 1e-5f + 1e-5f * fmaxf(fabsf(yv.z), fabsf(y1v.z)); q = ev / tol; sacc += q * q;
      ev = dtc * (E1C*k1v.w + E3C*k3v.w + E4C*k4v.w + E5C*k5v.w + E6C*k6v.w + E7C*k7v.w);
      tol = 1e-5f + 1e-5f * fmaxf(fabsf(yv.w), fabsf(y1v.w)); q = ev / tol; sacc += q * q;
    }
    if (tid < RB){
      float evl = dtc * (E1C * lds[L_KL + 0*32 + tid] + E3C * lds[L_KL + 2*32 + tid]
                + E4C * lds[L_KL + 3*32 + tid] + E5C * lds[L_KL + 4*32 + tid]
                + E6C * lds[L_KL + 5*32 + tid] + E7C * lds[L_KL + 6*32 + tid]);
      float toll = 1e-5f + 1e-5f * fmaxf(fabsf(lds[L_YL + tid]), fabsf(lds[L_Y1L + tid]));
      float ql = evl / toll; sacc += ql * ql;
    }
    // block reduction: wave butterflies + 8-wide LDS combine
#pragma unroll
    for (int mk = 1; mk < 64; mk <<= 1) sacc += __shfl_xor(sacc, mk, 64);
    if ((tid & 63) == 0) lds[L_RED + (tid >> 6)] = sacc;   // RED aliases dead H1W
    __syncthreads();
    if (tid == 0){
      float s = lds[L_RED+0] + lds[L_RED+1] + lds[L_RED+2] + lds[L_RED+3]
              + lds[L_RED+4] + lds[L_RED+5] + lds[L_RED+6] + lds[L_RED+7];
      ws[WS_PART + step * 256 + bid] = s;
    }

    grid.sync();

    // deterministic global reduction (every block, identical order)
    float ps = 0.f;
    if (tid < 256) ps = ws[WS_PART + step * 256 + tid];
#pragma unroll
    for (int mk = 1; mk < 64; mk <<= 1) ps += __shfl_xor(ps, mk, 64);
    if (tid < 256 && (tid & 63) == 0) lds[L_RED + (tid >> 6)] = ps;
    __syncthreads();
    const float errn = sqrtf((lds[L_RED+0] + lds[L_RED+1] + lds[L_RED+2] + lds[L_RED+3])
                             / 270336.0f);
    __syncthreads();             // protect RED(=H1W) before next phase-1 overwrite

    const bool accept = (errn <= 1.0f);
    if (accept){                               // wave-local y <- y1
      const int w = tid >> 6, lane = tid & 63;
      const int r = lane >> 4, c = (lane << 1) & 31;
      const int o = (4 * w + r) * 36 + c;
      *(f2*)&lds[L_YZ + o] = *(const f2*)&lds[L_Y1Z + o];
      if (lane < 4) lds[L_YL + 4 * w + lane] = lds[L_Y1L + 4 * w + lane];
      t_cur += dtc;
    }
    float fac = 0.9f * powf(errn, -0.2f);
    fac = fminf(fmaxf(fac, 0.2f), 10.0f);
    dt_cur = fminf(fmaxf(dtc * fac, 1e-6f), t1);
    prev_acc = accept;
  }

  // ---- output: yT[:, :d] ----
  __syncthreads();
  if (tid < 256){
    const int r = tid >> 3, jj = (tid & 7) * 4;
    st4(&out[(r0 + r) * 32 + jj], ld4(&lds[L_YZ + r * 36 + jj]));
  }
}

extern "C" void kernel_launch(void* const* d_in, const int* in_sizes, int n_in,
                              void* d_out, int out_size, void* d_ws, size_t ws_size,
                              hipStream_t stream)
{
  (void)in_sizes; (void)n_in; (void)out_size;
  const float* z  = (const float*)d_in[0];
  const float* Gw = (const float*)d_in[1];
  const float* W1 = (const float*)d_in[2];
  const float* b1 = (const float*)d_in[3];
  const float* W2 = (const float*)d_in[4];
  const float* b2 = (const float*)d_in[5];
  const float* W3 = (const float*)d_in[6];
  const float* b3 = (const float*)d_in[7];
  const float* T  = (const float*)d_in[8];
  float* out = (float*)d_out;
  float* ws  = (float*)d_ws;
  if (ws_size < (size_t)WS_TOTAL * sizeof(float)) return;

  void* args[] = { (void*)&z, (void*)&Gw, (void*)&W1, (void*)&b1, (void*)&W2,
                   (void*)&b2, (void*)&W3, (void*)&b3, (void*)&T, (void*)&out,
                   (void*)&ws };
  hipLaunchCooperativeKernel((const void*)qpnf_kernel, dim3(256), dim3(NT),
                             args, 0, stream);
}